// Round 1
// baseline (5071.653 us; speedup 1.0000x reference)
//
#include <hip/hip_runtime.h>
#include <hip/hip_bf16.h>
#include <math.h>

#define S_LEN 4096
#define HID 768
#define NHEAD 12
#define HDIM 64
#define NLAYER 2
#define WIN 256
#define FF 3072
#define N_ICD 8000
#define N_CPT 5000
#define N_CH 22

// ---------------- block reduce (deterministic) ----------------
__device__ __forceinline__ float breduce(float v, volatile float* red) {
    int t = threadIdx.x;
    #pragma unroll
    for (int o = 32; o > 0; o >>= 1) v += __shfl_down(v, o, 64);
    __syncthreads();
    if ((t & 63) == 0) red[t >> 6] = v;
    __syncthreads();
    float r = red[0] + red[1] + red[2] + red[3];
    return r;
}

// ---------------- embedding + LN ----------------
__global__ __launch_bounds__(256) void embed_ln_kernel(
    const int* __restrict__ ids, const float* __restrict__ we,
    const float* __restrict__ pe, const float* __restrict__ ls,
    const float* __restrict__ lb, float* __restrict__ x) {
    __shared__ float red[4];
    int srow = blockIdx.x, t = threadIdx.x;
    int id = ids[srow];
    float v[3];
    #pragma unroll
    for (int i = 0; i < 3; i++) {
        int hh = i * 256 + t;
        v[i] = we[(size_t)id * HID + hh] + pe[srow * HID + hh];
    }
    float s = v[0] + v[1] + v[2];
    float mean = breduce(s, red) * (1.f / HID);
    __syncthreads();
    float sq = 0.f;
    #pragma unroll
    for (int i = 0; i < 3; i++) { float d = v[i] - mean; sq += d * d; }
    float var = breduce(sq, red) * (1.f / HID);
    float inv = rsqrtf(var + 1e-5f);
    #pragma unroll
    for (int i = 0; i < 3; i++) {
        int hh = i * 256 + t;
        x[srow * HID + hh] = (v[i] - mean) * inv * ls[hh] + lb[hh];
    }
}

// ---------------- residual + LN (in-place on x) ----------------
__global__ __launch_bounds__(256) void residual_ln_kernel(
    float* __restrict__ x, const float* __restrict__ y,
    const float* __restrict__ ls, const float* __restrict__ lb) {
    __shared__ float red[4];
    int srow = blockIdx.x, t = threadIdx.x;
    float v[3];
    #pragma unroll
    for (int i = 0; i < 3; i++) {
        int hh = i * 256 + t;
        v[i] = x[srow * HID + hh] + y[srow * HID + hh];
    }
    float s = v[0] + v[1] + v[2];
    float mean = breduce(s, red) * (1.f / HID);
    __syncthreads();
    float sq = 0.f;
    #pragma unroll
    for (int i = 0; i < 3; i++) { float d = v[i] - mean; sq += d * d; }
    float var = breduce(sq, red) * (1.f / HID);
    float inv = rsqrtf(var + 1e-5f);
    #pragma unroll
    for (int i = 0; i < 3; i++) {
        int hh = i * 256 + t;
        x[srow * HID + hh] = (v[i] - mean) * inv * ls[hh] + lb[hh];
    }
}

// ---------------- generic fp32 GEMM: C = A(MxK) @ B(KxN) + bias, opt GELU ----------------
// grid (N/64, M/64), block 256. BM=BN=64, BK=16, 4x4 micro-tile.
template<int ACT>
__global__ __launch_bounds__(256) void gemm_bias_kernel(
    const float* __restrict__ A, const float* __restrict__ Bw,
    const float* __restrict__ bias, float* __restrict__ C,
    int M, int N, int K) {
    __shared__ float As[16][65];
    __shared__ float Bs[16][65];
    int bn = blockIdx.x, bm = blockIdx.y;
    int t = threadIdx.x;
    int tx = t & 15, ty = t >> 4;
    int m0 = bm * 64, n0 = bn * 64;
    float acc[4][4] = {};
    for (int k0 = 0; k0 < K; k0 += 16) {
        {
            int k = t & 15, m = t >> 4;
            #pragma unroll
            for (int i = 0; i < 4; i++) {
                int mm = m + i * 16;
                As[k][mm] = A[(size_t)(m0 + mm) * K + k0 + k];
            }
        }
        {
            int n = t & 63, k = t >> 6;
            #pragma unroll
            for (int i = 0; i < 4; i++) {
                int kk = k + i * 4;
                Bs[kk][n] = Bw[(size_t)(k0 + kk) * N + n0 + n];
            }
        }
        __syncthreads();
        #pragma unroll
        for (int k = 0; k < 16; k++) {
            float a[4], b[4];
            #pragma unroll
            for (int i = 0; i < 4; i++) a[i] = As[k][ty * 4 + i];
            #pragma unroll
            for (int j = 0; j < 4; j++) b[j] = Bs[k][tx * 4 + j];
            #pragma unroll
            for (int i = 0; i < 4; i++)
                #pragma unroll
                for (int j = 0; j < 4; j++) acc[i][j] += a[i] * b[j];
        }
        __syncthreads();
    }
    #pragma unroll
    for (int i = 0; i < 4; i++) {
        int row = m0 + ty * 4 + i;
        #pragma unroll
        for (int j = 0; j < 4; j++) {
            int col = n0 + tx * 4 + j;
            float val = acc[i][j] + bias[col];
            if (ACT == 1) {
                float x3 = val * val * val;
                val = 0.5f * val * (1.f + tanhf(0.7978845608028654f * (val + 0.044715f * x3)));
            }
            C[(size_t)row * N + col] = val;
        }
    }
}

// ---------------- band (sliding window) attention ----------------
// grid (S/32, H), block 256. Each block: 32 queries x 576-key strip.
#define QB 32
#define KTILES 9
__global__ __launch_bounds__(256) void band_attn_kernel(
    const float* __restrict__ q, const float* __restrict__ k,
    const float* __restrict__ v, const float* __restrict__ mask,
    float* __restrict__ ctx) {
    __shared__ float Qs[QB][65];
    __shared__ float Ks[64][65];
    __shared__ float Sc[QB][584];  // 576 used, padded stride to break bank conflicts
    int qblk = blockIdx.x, h = blockIdx.y;
    int qbase = qblk * QB;
    int kbase = qbase - WIN;
    int t = threadIdx.x;
    int r = t >> 3, sub = t & 7;

    for (int i = t; i < QB * 64; i += 256) {
        int rr = i >> 6, d = i & 63;
        Qs[rr][d] = q[(size_t)(qbase + rr) * HID + h * 64 + d];
    }
    const float scale = 0.125f;
    int qp = qbase + r;

    // scores
    for (int kt = 0; kt < KTILES; kt++) {
        __syncthreads();
        for (int i = t; i < 64 * 64; i += 256) {
            int kr = i >> 6, d = i & 63;
            int kp = kbase + kt * 64 + kr;
            Ks[kr][d] = (kp >= 0 && kp < S_LEN) ? k[(size_t)kp * HID + h * 64 + d] : 0.f;
        }
        __syncthreads();
        float accs[8] = {};
        #pragma unroll
        for (int d = 0; d < 64; d++) {
            float qv = Qs[r][d];
            #pragma unroll
            for (int j = 0; j < 8; j++) accs[j] += qv * Ks[sub + 8 * j][d];
        }
        #pragma unroll
        for (int j = 0; j < 8; j++) {
            int krel = kt * 64 + sub + 8 * j;
            int kp = kbase + krel;
            bool ok = (kp >= 0) && (kp < S_LEN) && (kp >= qp - WIN) && (kp <= qp + WIN);
            if (ok) ok = mask[kp] > 0.5f;
            Sc[r][krel] = ok ? accs[j] * scale : -1e9f;
        }
    }
    __syncthreads();

    // softmax over 576 per row (8 threads/row)
    float m = -1e30f;
    for (int c = sub; c < 576; c += 8) m = fmaxf(m, Sc[r][c]);
    #pragma unroll
    for (int o = 1; o < 8; o <<= 1) m = fmaxf(m, __shfl_xor(m, o, 8));
    float ssum = 0.f;
    for (int c = sub; c < 576; c += 8) {
        float e = expf(Sc[r][c] - m);
        Sc[r][c] = e;
        ssum += e;
    }
    #pragma unroll
    for (int o = 1; o < 8; o <<= 1) ssum += __shfl_xor(ssum, o, 8);
    float inv = 1.0f / ssum;
    for (int c = sub; c < 576; c += 8) Sc[r][c] *= inv;

    // PV
    float acc[8] = {};
    for (int kt = 0; kt < KTILES; kt++) {
        __syncthreads();
        for (int i = t; i < 64 * 64; i += 256) {
            int kr = i >> 6, d = i & 63;
            int kp = kbase + kt * 64 + kr;
            Ks[kr][d] = (kp >= 0 && kp < S_LEN) ? v[(size_t)kp * HID + h * 64 + d] : 0.f;
        }
        __syncthreads();
        #pragma unroll
        for (int kk = 0; kk < 64; kk++) {
            float p = Sc[r][kt * 64 + kk];
            #pragma unroll
            for (int j = 0; j < 8; j++) acc[j] += p * Ks[kk][sub * 8 + j];
        }
    }
    #pragma unroll
    for (int j = 0; j < 8; j++)
        ctx[(size_t)(qbase + r) * HID + h * 64 + sub * 8 + j] = acc[j];
}

// ---------------- classifier head: out = pooled(768) @ W(768xN) + b ----------------
__global__ __launch_bounds__(256) void head_logits_kernel(
    const float* __restrict__ x0, const float* __restrict__ Wt,
    const float* __restrict__ bias, float* __restrict__ out, int N) {
    __shared__ float p[HID];
    int t = threadIdx.x;
    for (int i = t; i < HID; i += 256) p[i] = x0[i];
    __syncthreads();
    int n = blockIdx.x * 256 + t;
    if (n < N) {
        float acc = bias[n];
        for (int hh = 0; hh < HID; hh++) acc += p[hh] * Wt[(size_t)hh * N + n];
        out[n] = acc;
    }
}

// ---------------- focal loss partials (deterministic tree) ----------------
__global__ __launch_bounds__(256) void focal_partial_kernel(
    const float* __restrict__ logits, const float* __restrict__ tgt,
    int N, float* __restrict__ partials) {
    __shared__ float red[256];
    int t = threadIdx.x;
    float s = 0.f;
    for (int i = blockIdx.x * 256 + t; i < N; i += gridDim.x * 256) {
        float l = logits[i], y = tgt[i];
        float bce = fmaxf(l, 0.f) - l * y + log1pf(expf(-fabsf(l)));
        float pt = expf(-bce);
        float om = 1.f - pt;
        s += om * om * bce;
    }
    red[t] = s;
    __syncthreads();
    for (int o = 128; o > 0; o >>= 1) {
        if (t < o) red[t] += red[t + o];
        __syncthreads();
    }
    if (t == 0) partials[blockIdx.x] = red[0];
}

__global__ void final_loss_kernel(const float* __restrict__ parts, float* __restrict__ out) {
    if (threadIdx.x == 0 && blockIdx.x == 0) {
        float a = 0.f, b = 0.f, c = 0.f;
        for (int i = 0; i < 32; i++) a += parts[i];
        for (int i = 0; i < 32; i++) b += parts[32 + i];
        for (int i = 0; i < 32; i++) c += parts[64 + i];
        out[0] = a / (float)N_ICD + b / (float)N_CPT + c / (float)N_CH;
    }
}

// ---------------- launch ----------------
extern "C" void kernel_launch(void* const* d_in, const int* in_sizes, int n_in,
                              void* d_out, int out_size, void* d_ws, size_t ws_size,
                              hipStream_t stream) {
    const int*   ids      = (const int*)d_in[0];
    const float* mask     = (const float*)d_in[1];
    const float* icd_lab  = (const float*)d_in[2];
    const float* cpt_lab  = (const float*)d_in[3];
    const float* ch_lab   = (const float*)d_in[4];
    const float* we       = (const float*)d_in[5];
    const float* pe       = (const float*)d_in[6];
    const float* els      = (const float*)d_in[7];
    const float* elb      = (const float*)d_in[8];
    const float* Wq       = (const float*)d_in[9];
    const float* bq       = (const float*)d_in[10];
    const float* Wk       = (const float*)d_in[11];
    const float* bk       = (const float*)d_in[12];
    const float* Wv       = (const float*)d_in[13];
    const float* bv       = (const float*)d_in[14];
    const float* Wo       = (const float*)d_in[15];
    const float* bo       = (const float*)d_in[16];
    const float* l1s      = (const float*)d_in[17];
    const float* l1b      = (const float*)d_in[18];
    const float* Wi       = (const float*)d_in[19];
    const float* bi       = (const float*)d_in[20];
    const float* Wo2      = (const float*)d_in[21];
    const float* bo2      = (const float*)d_in[22];
    const float* l2s      = (const float*)d_in[23];
    const float* l2b      = (const float*)d_in[24];
    const float* W_icd    = (const float*)d_in[25];
    const float* b_icd    = (const float*)d_in[26];
    const float* W_cpt    = (const float*)d_in[27];
    const float* b_cpt    = (const float*)d_in[28];
    const float* W_ch     = (const float*)d_in[29];
    const float* b_ch     = (const float*)d_in[30];

    const size_t SH = (size_t)S_LEN * HID;
    float* ws   = (float*)d_ws;
    float* x    = ws;
    float* qb   = x + SH;
    float* kb   = qb + SH;
    float* vb   = kb + SH;
    float* ctx  = vb + SH;
    float* tmp  = ctx + SH;
    float* ffh  = tmp + SH;
    float* chl  = ffh + (size_t)S_LEN * FF;
    float* parts = chl + 32;

    float* out = (float*)d_out;
    float* icd_logits = out + 1;
    float* cpt_logits = out + 1 + N_ICD;

    embed_ln_kernel<<<S_LEN, 256, 0, stream>>>(ids, we, pe, els, elb, x);

    for (int l = 0; l < NLAYER; l++) {
        const float* wq = Wq + (size_t)l * HID * HID;
        const float* wk = Wk + (size_t)l * HID * HID;
        const float* wv = Wv + (size_t)l * HID * HID;
        const float* wo = Wo + (size_t)l * HID * HID;
        const float* wi = Wi + (size_t)l * HID * FF;
        const float* wo2 = Wo2 + (size_t)l * FF * HID;

        dim3 g1(HID / 64, S_LEN / 64);
        gemm_bias_kernel<0><<<g1, 256, 0, stream>>>(x, wq, bq + l * HID, qb, S_LEN, HID, HID);
        gemm_bias_kernel<0><<<g1, 256, 0, stream>>>(x, wk, bk + l * HID, kb, S_LEN, HID, HID);
        gemm_bias_kernel<0><<<g1, 256, 0, stream>>>(x, wv, bv + l * HID, vb, S_LEN, HID, HID);

        band_attn_kernel<<<dim3(S_LEN / QB, NHEAD), 256, 0, stream>>>(qb, kb, vb, mask, ctx);

        gemm_bias_kernel<0><<<g1, 256, 0, stream>>>(ctx, wo, bo + l * HID, tmp, S_LEN, HID, HID);
        residual_ln_kernel<<<S_LEN, 256, 0, stream>>>(x, tmp, l1s + l * HID, l1b + l * HID);

        gemm_bias_kernel<1><<<dim3(FF / 64, S_LEN / 64), 256, 0, stream>>>(x, wi, bi + l * FF, ffh, S_LEN, FF, HID);
        gemm_bias_kernel<0><<<g1, 256, 0, stream>>>(ffh, wo2, bo2 + l * HID, tmp, S_LEN, HID, FF);
        residual_ln_kernel<<<S_LEN, 256, 0, stream>>>(x, tmp, l2s + l * HID, l2b + l * HID);
    }

    head_logits_kernel<<<(N_ICD + 255) / 256, 256, 0, stream>>>(x, W_icd, b_icd, icd_logits, N_ICD);
    head_logits_kernel<<<(N_CPT + 255) / 256, 256, 0, stream>>>(x, W_cpt, b_cpt, cpt_logits, N_CPT);
    head_logits_kernel<<<1, 256, 0, stream>>>(x, W_ch, b_ch, chl, N_CH);

    focal_partial_kernel<<<32, 256, 0, stream>>>(icd_logits, icd_lab, N_ICD, parts);
    focal_partial_kernel<<<32, 256, 0, stream>>>(cpt_logits, cpt_lab, N_CPT, parts + 32);
    focal_partial_kernel<<<32, 256, 0, stream>>>(chl, ch_lab, N_CH, parts + 64);
    final_loss_kernel<<<1, 1, 0, stream>>>(parts, out);
}